// Round 5
// baseline (293.487 us; speedup 1.0000x reference)
//
#include <hip/hip_runtime.h>
#include <stdint.h>

#define N_ANCH 33600
#define BS 16
#define NCH 56
#define MAX_NMS 3000
#define MAX_DET 300
#define CONF_T 0.25f
#define IOU_T 0.7f
#define IMG 1280.0f
#define NW 47                         // 47*64 = 3008 >= 3000 bits
#define NBINS 4096
#define HIST_BINS 4097
#define CAP 4096                      // candidate slots per image
#define WCAP 4096                     // worklist entries per image
#define WC_STRIDE 16                  // wcount padded to 64B per image

// ---- ws layout (bytes) ---- (no memset needed; everything written before read)
#define OFF_CAND 0                                   // 16*4096*8 = 524288
#define OFF_WL   (OFF_CAND + BS*CAP*8)               // 16*4096*4 = 262144
#define OFF_WC   (OFF_WL + BS*WCAP*4)                // 16*16*4 = 1024
#define OFF_OIDX (OFF_WC + BS*WC_STRIDE*4)           // 16*3000*4
#define OFF_SC   (OFF_OIDX + BS*MAX_NMS*4)           // 16*3000*4
#define OFF_BOX  (OFF_SC + BS*MAX_NMS*4)             // 16*3000*16 (offset %16==0)

__device__ __forceinline__ int score_bucket(float c, uint32_t* bits_out) {
    if (!(c > CONF_T)) { *bits_out = 0u; return 0; }
    uint32_t bits = __float_as_uint(c);
    *bits_out = bits;
    int bucket = (int)(bits >> 12) - 0x3E800 + 1;
    bucket = bucket < 1 ? 1 : (bucket > NBINS ? NBINS : bucket);
    return bucket;
}

// ---- Phase 1 (one block per image): hist + scan + worklist + scatter + pad ----
__global__ void k_phase1(const float* __restrict__ preds,
                         unsigned long long* __restrict__ cand,
                         unsigned int* __restrict__ wlist, int* __restrict__ wcount,
                         int* __restrict__ oidx, float* __restrict__ sc_out,
                         float4* __restrict__ box_out) {
    __shared__ int hl[HIST_BINS];     // counts
    __shared__ int st[HIST_BINS];     // start offsets, later scatter cursors
    __shared__ int part[256];
    __shared__ int suf[256];
    __shared__ int ldsB, ldsM, ldsWc;
    int b = blockIdx.x, t = threadIdx.x;       // 1024 threads
    if (t == 0) { ldsWc = 0; }
    for (int i = t; i < HIST_BINS; i += 1024) hl[i] = 0;
    __syncthreads();
    const float* conf = preds + (size_t)b * NCH * N_ANCH + 4 * N_ANCH;
    for (int a = t; a < N_ANCH; a += 1024) {
        uint32_t bits;
        int bucket = score_bucket(conf[a], &bits);
        if (bucket > 0) atomicAdd(&hl[bucket], 1);
    }
    __syncthreads();
    if (t < 256) {
        int s = 0;
        for (int k = 0; k < 16; k++) s += hl[1 + t * 16 + k];
        part[t] = s;
    }
    __syncthreads();
    if (t == 0) {
        int run = 0;
        for (int i = 255; i >= 0; i--) { suf[i] = run; run += part[i]; }
        if (run < MAX_NMS) { ldsB = 1; ldsM = run; }   // fewer than 3000 valid
    }
    __syncthreads();
    if (t < 256) {
        int run = suf[t];
        bool maycross = (run < MAX_NMS) && (run + part[t] >= MAX_NMS);
        bool done = false;
        for (int k = 15; k >= 0; k--) {
            int bin = 1 + t * 16 + k;
            st[bin] = run;
            run += hl[bin];
            if (maycross && !done && run >= MAX_NMS) { ldsB = bin; ldsM = run; done = true; }
        }
    }
    __syncthreads();
    int B = ldsB, M = ldsM;
    // worklist of segments that intersect the top-3000
    if (t < 256) {
        for (int k = 0; k < 16; k++) {
            int bin = 1 + t * 16 + k;
            int c = hl[bin], s = st[bin];
            if (c > 0 && bin >= B && s < MAX_NMS) {
                int idx = atomicAdd(&ldsWc, 1);
                wlist[b * WCAP + idx] = (unsigned int)s | ((unsigned int)c << 16);
            }
        }
    }
    __syncthreads();
    // scatter pass (st doubles as cursor)
    for (int a = t; a < N_ANCH; a += 1024) {
        uint32_t bits;
        int bucket = score_bucket(conf[a], &bits);
        if (bucket >= B && bucket > 0) {
            int pos = atomicAdd(&st[bucket], 1);
            if (pos < CAP)
                cand[b * CAP + pos] =
                    ((unsigned long long)bits << 32) | (uint32_t)(~(uint32_t)a);
        }
    }
    // pad [M, 3000) with invalid entries
    for (int p = M + t; p < MAX_NMS; p += 1024) {
        sc_out[b * MAX_NMS + p] = -1.0f;
        box_out[b * MAX_NMS + p] = make_float4(0.f, 0.f, 0.f, 0.f);
        oidx[b * MAX_NMS + p] = 0;
    }
    if (t == 0) wcount[b * WC_STRIDE] = ldsWc;
}

// ---- Phase 2: rank within segments + write clipped boxes at final positions ----
__global__ void k_rank2(const float* __restrict__ preds,
                        const unsigned long long* __restrict__ cand,
                        const unsigned int* __restrict__ wlist,
                        const int* __restrict__ wcount,
                        int* __restrict__ oidx, float* __restrict__ sc_out,
                        float4* __restrict__ box_out) {
    int b = blockIdx.x;
    int wc = wcount[b * WC_STRIDE];
    int wv = blockIdx.y * (blockDim.x >> 6) + (threadIdx.x >> 6);  // wave id in image
    int lane = threadIdx.x & 63;
    const int wstride = gridDim.y * (blockDim.x >> 6);
    const float* pr = preds + (size_t)b * NCH * N_ANCH;
    for (int e = wv; e < wc; e += wstride) {
        unsigned int ent = wlist[b * WCAP + e];
        int s = (int)(ent & 0xffffu);
        int n = (int)(ent >> 16);
        if (s + n > CAP) n = CAP - s;
        const unsigned long long* seg = cand + b * CAP + s;
        for (int i = lane; i < n; i += 64) {
            unsigned long long ke = seg[i];
            int r = 0;
            for (int j = 0; j < n; j++) r += (seg[j] > ke);
            int pos = s + r;
            if (pos < MAX_NMS) {
                int oi = (int)(~(uint32_t)ke);
                float score = __uint_as_float((uint32_t)(ke >> 32));
                float cx = pr[0 * N_ANCH + oi], cy = pr[1 * N_ANCH + oi];
                float w  = pr[2 * N_ANCH + oi], h  = pr[3 * N_ANCH + oi];
                float4 bx;
                bx.x = fminf(fmaxf(cx - w * 0.5f, 0.f), IMG);
                bx.y = fminf(fmaxf(cy - h * 0.5f, 0.f), IMG);
                bx.z = fminf(fmaxf(cx + w * 0.5f, 0.f), IMG);
                bx.w = fminf(fmaxf(cy + h * 0.5f, 0.f), IMG);
                oidx[b * MAX_NMS + pos] = oi;
                sc_out[b * MAX_NMS + pos] = score;
                box_out[b * MAX_NMS + pos] = bx;
            }
        }
    }
}

__device__ __forceinline__ float iou_pair(float4 bi, float ai, float4 bj) {
    float aj  = (bj.z - bj.x) * (bj.w - bj.y);
    float ltx = fmaxf(bi.x, bj.x), lty = fmaxf(bi.y, bj.y);
    float rbx = fminf(bi.z, bj.z), rby = fminf(bi.w, bj.w);
    float wx  = fmaxf(rbx - ltx, 0.f), wy = fmaxf(rby - lty, 0.f);
    float inter = wx * wy;
    return inter / (ai + aj - inter + 1e-9f);
}

__device__ __forceinline__ unsigned long long readlane64(unsigned long long v, int lane) {
    uint32_t lo = (uint32_t)v, hi = (uint32_t)(v >> 32);
    uint32_t rlo = __builtin_amdgcn_readlane(lo, lane);
    uint32_t rhi = __builtin_amdgcn_readlane(hi, lane);
    return ((unsigned long long)rhi << 32) | (unsigned long long)rlo;
}

// ---- Phase 3: pull-model greedy NMS (early exit at 300) + fused output write ----
__global__ void k_nms_out(const float* __restrict__ preds,
                          const float4* __restrict__ box_ws, const float* __restrict__ sc_ws,
                          const int* __restrict__ oidx_ws, float* __restrict__ out) {
    __shared__ float4 lbox[MAX_NMS];
    __shared__ float4 kbox[MAX_DET];
    __shared__ float  karea[MAX_DET];
    __shared__ int    lsel[MAX_DET];
    __shared__ unsigned long long pres[NW];
    __shared__ unsigned long long diag[64];
    __shared__ unsigned long long keptmask_sh;
    int b = blockIdx.x, t = threadIdx.x;
    if (t < NW) pres[t] = 0ull;
    __syncthreads();
    for (int j = t; j < MAX_NMS; j += 1024) {
        lbox[j] = box_ws[b * MAX_NMS + j];
        if (!(sc_ws[b * MAX_NMS + j] > CONF_T))
            atomicOr(&pres[j >> 6], 1ull << (j & 63));
    }
    __syncthreads();
    int kc = 0;
    for (int c = 0; c < NW && kc < MAX_DET; c++) {
        int base = c * 64;
        if (t < 64) diag[t] = 0ull;
        __syncthreads();
        {   // suppression of chunk boxes by already-kept boxes (pull)
            int jl = t >> 4, kk = t & 15;
            int j = base + jl;
            if (j < MAX_NMS && kc > 0) {
                float4 bj = lbox[j];
                bool sup = false;
                for (int kidx = kk; kidx < kc; kidx += 16) {
                    if (iou_pair(kbox[kidx], karea[kidx], bj) > IOU_T) { sup = true; break; }
                }
                if (sup) atomicOr(&pres[c], 1ull << jl);
            }
        }
        {   // intra-chunk 64x64
            int il = t >> 4;
            int j0 = (t & 15) * 4;
            int i = base + il;
            if (i < MAX_NMS) {
                float4 bi = lbox[i];
                float ai = (bi.z - bi.x) * (bi.w - bi.y);
                unsigned long long m = 0ull;
                for (int q = 0; q < 4; q++) {
                    int jl = j0 + q, j = base + jl;
                    if (j > i && j < MAX_NMS) {
                        if (iou_pair(bi, ai, lbox[j]) > IOU_T) m |= 1ull << jl;
                    }
                }
                if (m) atomicOr(&diag[il], m);
            }
        }
        __syncthreads();
        if (t < 64) {   // greedy bit loop on wave 0, diag via readlane
            unsigned long long mydiag = diag[t];
            unsigned long long s = pres[c];
            unsigned long long keptm = 0ull;
            int room = MAX_DET - kc;
            int jmax = MAX_NMS - base; if (jmax > 64) jmax = 64;
            for (int bb = 0; bb < jmax; bb++) {
                if (!((s >> bb) & 1ull)) {
                    s |= readlane64(mydiag, bb);
                    keptm |= 1ull << bb;
                    if (--room == 0) break;
                }
            }
            if (t == 0) keptmask_sh = keptm;
        }
        __syncthreads();
        unsigned long long keptm = keptmask_sh;
        if (t < 64 && ((keptm >> t) & 1ull)) {
            int pos = kc + __popcll(keptm & ((1ull << t) - 1ull));
            float4 bx = lbox[base + t];
            kbox[pos] = bx;
            karea[pos] = (bx.z - bx.x) * (bx.w - bx.y);
            lsel[pos] = base + t;
        }
        kc += __popcll(keptm);
        __syncthreads();
    }
    // ---- fused output write for image b ----
    float* ob  = out;                       // (16,300,4)
    float* osc = out + BS * MAX_DET * 4;    // (16,300,1)
    float* okp = out + BS * MAX_DET * 5;    // (16,300,51)
    const float* pr = preds + (size_t)b * NCH * N_ANCH;
    for (int g = t; g < MAX_DET * 64; g += 1024) {
        int r = g >> 6, lane = g & 63;
        int det = b * MAX_DET + r;
        if (r < kc) {
            int s = lsel[r];
            if (lane < 4) {
                float4 bx = kbox[r];
                float v = (lane == 0) ? bx.x : (lane == 1) ? bx.y : (lane == 2) ? bx.z : bx.w;
                ob[det * 4 + lane] = v;
            } else if (lane == 4) {
                osc[det] = sc_ws[b * MAX_NMS + s];
            } else if (lane < 56) {
                int k = lane - 5;
                int oi = oidx_ws[b * MAX_NMS + s];
                float v = pr[(size_t)(5 + k) * N_ANCH + oi];
                if (k < 2) v = fminf(fmaxf(v, 0.f), IMG);   // ref clips only cols 0,1
                okp[det * 51 + k] = v;
            }
        } else {
            if (lane < 4)       ob[det * 4 + lane] = 0.f;
            else if (lane == 4) osc[det] = 0.f;
            else if (lane < 56) okp[det * 51 + (lane - 5)] = 0.f;
        }
    }
}

extern "C" void kernel_launch(void* const* d_in, const int* in_sizes, int n_in,
                              void* d_out, int out_size, void* d_ws, size_t ws_size,
                              hipStream_t stream) {
    const float* preds = (const float*)d_in[0];
    float* out = (float*)d_out;
    char* ws = (char*)d_ws;
    unsigned long long* cand = (unsigned long long*)(ws + OFF_CAND);
    unsigned int* wlist = (unsigned int*)(ws + OFF_WL);
    int* wcount = (int*)(ws + OFF_WC);
    int* oidx = (int*)(ws + OFF_OIDX);
    float* sc = (float*)(ws + OFF_SC);
    float4* box = (float4*)(ws + OFF_BOX);

    k_phase1<<<BS, 1024, 0, stream>>>(preds, cand, wlist, wcount, oidx, sc, box);
    k_rank2<<<dim3(BS, 32), 256, 0, stream>>>(preds, cand, wlist, wcount, oidx, sc, box);
    k_nms_out<<<BS, 1024, 0, stream>>>(preds, box, sc, oidx, out);
}

// Round 6
// 230.094 us; speedup vs baseline: 1.2755x; 1.2755x over previous
//
#include <hip/hip_runtime.h>
#include <stdint.h>

#define N_ANCH 33600
#define BS 16
#define NCH 56
#define MAX_NMS 3000
#define MAX_DET 300
#define CONF_T 0.25f
#define IOU_T 0.7f
#define IMG 1280.0f
#define NW 47                         // 47*64 = 3008 >= 3000 bits
#define NBINS 4096
#define HIST_BINS 4097
#define CAP 4096                      // candidate slots per image
#define WCAP 4096                     // worklist entries per image
#define WC_STRIDE 16                  // wcount padded to 64B per image

// ---- ws layout (bytes) ---- (no memset needed; everything written before read)
#define OFF_CAND 0                                   // 16*4096*8 = 524288
#define OFF_WL   (OFF_CAND + BS*CAP*8)               // 16*4096*4 = 262144
#define OFF_WC   (OFF_WL + BS*WCAP*4)                // 16*16*4 = 1024
#define OFF_KEPT (OFF_WC + BS*WC_STRIDE*4)           // 16*4 -> pad 64
#define OFF_OIDX (OFF_KEPT + 64)                     // 16*3000*4
#define OFF_SC   (OFF_OIDX + BS*MAX_NMS*4)           // 16*3000*4
#define OFF_SEL  (OFF_SC + BS*MAX_NMS*4)             // 16*300*4
#define OFF_BOX  (((OFF_SEL + BS*MAX_DET*4) + 15) & ~15)  // 16*3000*16, 16B aligned

__device__ __forceinline__ int score_bucket(float c, uint32_t* bits_out) {
    if (!(c > CONF_T)) { *bits_out = 0u; return 0; }
    uint32_t bits = __float_as_uint(c);
    *bits_out = bits;
    int bucket = (int)(bits >> 12) - 0x3E800 + 1;
    bucket = bucket < 1 ? 1 : (bucket > NBINS ? NBINS : bucket);
    return bucket;
}

// ---- Phase 1 (one block per image): hist + scan + worklist + scatter + pad ----
__global__ void k_phase1(const float* __restrict__ preds,
                         unsigned long long* __restrict__ cand,
                         unsigned int* __restrict__ wlist, int* __restrict__ wcount,
                         int* __restrict__ oidx, float* __restrict__ sc_out,
                         float4* __restrict__ box_out) {
    __shared__ int hl[HIST_BINS];     // counts
    __shared__ int st[HIST_BINS];     // start offsets, later scatter cursors
    __shared__ int part[256];
    __shared__ int suf[256];
    __shared__ int ldsB, ldsM, ldsWc;
    int b = blockIdx.x, t = threadIdx.x;       // 1024 threads
    if (t == 0) { ldsWc = 0; }
    for (int i = t; i < HIST_BINS; i += 1024) hl[i] = 0;
    __syncthreads();
    const float4* conf4 = (const float4*)(preds + (size_t)b * NCH * N_ANCH + 4 * N_ANCH);
    for (int a4 = t; a4 < N_ANCH / 4; a4 += 1024) {     // 33600 % 4 == 0
        float4 c4 = conf4[a4];
        uint32_t bits;
        int bk;
        bk = score_bucket(c4.x, &bits); if (bk > 0) atomicAdd(&hl[bk], 1);
        bk = score_bucket(c4.y, &bits); if (bk > 0) atomicAdd(&hl[bk], 1);
        bk = score_bucket(c4.z, &bits); if (bk > 0) atomicAdd(&hl[bk], 1);
        bk = score_bucket(c4.w, &bits); if (bk > 0) atomicAdd(&hl[bk], 1);
    }
    __syncthreads();
    if (t < 256) {
        int s = 0;
        for (int k = 0; k < 16; k++) s += hl[1 + t * 16 + k];
        part[t] = s;
    }
    __syncthreads();
    if (t == 0) {
        int run = 0;
        for (int i = 255; i >= 0; i--) { suf[i] = run; run += part[i]; }
        if (run < MAX_NMS) { ldsB = 1; ldsM = run; }   // fewer than 3000 valid
    }
    __syncthreads();
    if (t < 256) {
        int run = suf[t];
        bool maycross = (run < MAX_NMS) && (run + part[t] >= MAX_NMS);
        bool done = false;
        for (int k = 15; k >= 0; k--) {
            int bin = 1 + t * 16 + k;
            st[bin] = run;
            run += hl[bin];
            if (maycross && !done && run >= MAX_NMS) { ldsB = bin; ldsM = run; done = true; }
        }
    }
    __syncthreads();
    int B = ldsB, M = ldsM;
    // worklist of segments that intersect the top-3000
    if (t < 256) {
        for (int k = 0; k < 16; k++) {
            int bin = 1 + t * 16 + k;
            int c = hl[bin], s = st[bin];
            if (c > 0 && bin >= B && s < MAX_NMS) {
                int idx = atomicAdd(&ldsWc, 1);
                wlist[b * WCAP + idx] = (unsigned int)s | ((unsigned int)c << 16);
            }
        }
    }
    __syncthreads();
    // scatter pass (st doubles as cursor); float4 re-read (L2-hot)
    for (int a4 = t; a4 < N_ANCH / 4; a4 += 1024) {
        float4 c4 = conf4[a4];
        float cv[4] = {c4.x, c4.y, c4.z, c4.w};
        #pragma unroll
        for (int q = 0; q < 4; q++) {
            uint32_t bits;
            int bucket = score_bucket(cv[q], &bits);
            if (bucket >= B && bucket > 0) {
                int pos = atomicAdd(&st[bucket], 1);
                if (pos < CAP) {
                    int a = a4 * 4 + q;
                    cand[b * CAP + pos] =
                        ((unsigned long long)bits << 32) | (uint32_t)(~(uint32_t)a);
                }
            }
        }
    }
    // pad [M, 3000) with invalid entries
    for (int p = M + t; p < MAX_NMS; p += 1024) {
        sc_out[b * MAX_NMS + p] = -1.0f;
        box_out[b * MAX_NMS + p] = make_float4(0.f, 0.f, 0.f, 0.f);
        oidx[b * MAX_NMS + p] = 0;
    }
    if (t == 0) wcount[b * WC_STRIDE] = ldsWc;
}

// ---- Phase 2: rank within segments + write clipped boxes at final positions ----
__global__ void k_rank2(const float* __restrict__ preds,
                        const unsigned long long* __restrict__ cand,
                        const unsigned int* __restrict__ wlist,
                        const int* __restrict__ wcount,
                        int* __restrict__ oidx, float* __restrict__ sc_out,
                        float4* __restrict__ box_out) {
    int b = blockIdx.x;
    int wc = wcount[b * WC_STRIDE];
    int wv = blockIdx.y * (blockDim.x >> 6) + (threadIdx.x >> 6);  // wave id in image
    int lane = threadIdx.x & 63;
    const int wstride = gridDim.y * (blockDim.x >> 6);
    const float* pr = preds + (size_t)b * NCH * N_ANCH;
    for (int e = wv; e < wc; e += wstride) {
        unsigned int ent = wlist[b * WCAP + e];
        int s = (int)(ent & 0xffffu);
        int n = (int)(ent >> 16);
        if (s + n > CAP) n = CAP - s;
        const unsigned long long* seg = cand + b * CAP + s;
        for (int i = lane; i < n; i += 64) {
            unsigned long long ke = seg[i];
            int r = 0;
            for (int j = 0; j < n; j++) r += (seg[j] > ke);
            int pos = s + r;
            if (pos < MAX_NMS) {
                int oi = (int)(~(uint32_t)ke);
                float score = __uint_as_float((uint32_t)(ke >> 32));
                float cx = pr[0 * N_ANCH + oi], cy = pr[1 * N_ANCH + oi];
                float w  = pr[2 * N_ANCH + oi], h  = pr[3 * N_ANCH + oi];
                float4 bx;
                bx.x = fminf(fmaxf(cx - w * 0.5f, 0.f), IMG);
                bx.y = fminf(fmaxf(cy - h * 0.5f, 0.f), IMG);
                bx.z = fminf(fmaxf(cx + w * 0.5f, 0.f), IMG);
                bx.w = fminf(fmaxf(cy + h * 0.5f, 0.f), IMG);
                oidx[b * MAX_NMS + pos] = oi;
                sc_out[b * MAX_NMS + pos] = score;
                box_out[b * MAX_NMS + pos] = bx;
            }
        }
    }
}

__device__ __forceinline__ float iou_pair(float4 bi, float ai, float4 bj) {
    float aj  = (bj.z - bj.x) * (bj.w - bj.y);
    float ltx = fmaxf(bi.x, bj.x), lty = fmaxf(bi.y, bj.y);
    float rbx = fminf(bi.z, bj.z), rby = fminf(bi.w, bj.w);
    float wx  = fmaxf(rbx - ltx, 0.f), wy = fmaxf(rby - lty, 0.f);
    float inter = wx * wy;
    return inter / (ai + aj - inter + 1e-9f);
}

__device__ __forceinline__ unsigned long long readlane64(unsigned long long v, int lane) {
    uint32_t lo = (uint32_t)v, hi = (uint32_t)(v >> 32);
    uint32_t rlo = __builtin_amdgcn_readlane(lo, lane);
    uint32_t rhi = __builtin_amdgcn_readlane(hi, lane);
    return ((unsigned long long)rhi << 32) | (unsigned long long)rlo;
}

// ---- Phase 3: pull-model greedy NMS (early exit at 300); writes sel/kept + box/score out ----
__global__ void k_nms(const float4* __restrict__ box_ws, const float* __restrict__ sc_ws,
                      int* __restrict__ sel_slot, int* __restrict__ kept_count,
                      float* __restrict__ out) {
    __shared__ float4 lbox[MAX_NMS];
    __shared__ float4 kbox[MAX_DET];
    __shared__ float  karea[MAX_DET];
    __shared__ int    lsel[MAX_DET];
    __shared__ unsigned long long pres[NW];
    __shared__ unsigned long long diag[64];
    __shared__ unsigned long long keptmask_sh;
    int b = blockIdx.x, t = threadIdx.x;
    if (t < NW) pres[t] = 0ull;
    __syncthreads();
    for (int j = t; j < MAX_NMS; j += 1024) {
        lbox[j] = box_ws[b * MAX_NMS + j];
        if (!(sc_ws[b * MAX_NMS + j] > CONF_T))
            atomicOr(&pres[j >> 6], 1ull << (j & 63));
    }
    __syncthreads();
    int kc = 0;
    for (int c = 0; c < NW && kc < MAX_DET; c++) {
        int base = c * 64;
        if (t < 64) diag[t] = 0ull;
        __syncthreads();
        {   // suppression of chunk boxes by already-kept boxes (pull)
            int jl = t >> 4, kk = t & 15;
            int j = base + jl;
            if (j < MAX_NMS && kc > 0) {
                float4 bj = lbox[j];
                bool sup = false;
                for (int kidx = kk; kidx < kc; kidx += 16) {
                    if (iou_pair(kbox[kidx], karea[kidx], bj) > IOU_T) { sup = true; break; }
                }
                if (sup) atomicOr(&pres[c], 1ull << jl);
            }
        }
        {   // intra-chunk 64x64
            int il = t >> 4;
            int j0 = (t & 15) * 4;
            int i = base + il;
            if (i < MAX_NMS) {
                float4 bi = lbox[i];
                float ai = (bi.z - bi.x) * (bi.w - bi.y);
                unsigned long long m = 0ull;
                for (int q = 0; q < 4; q++) {
                    int jl = j0 + q, j = base + jl;
                    if (j > i && j < MAX_NMS) {
                        if (iou_pair(bi, ai, lbox[j]) > IOU_T) m |= 1ull << jl;
                    }
                }
                if (m) atomicOr(&diag[il], m);
            }
        }
        __syncthreads();
        if (t < 64) {   // greedy bit loop on wave 0, diag via readlane
            unsigned long long mydiag = diag[t];
            unsigned long long s = pres[c];
            unsigned long long keptm = 0ull;
            int room = MAX_DET - kc;
            int jmax = MAX_NMS - base; if (jmax > 64) jmax = 64;
            for (int bb = 0; bb < jmax; bb++) {
                if (!((s >> bb) & 1ull)) {
                    s |= readlane64(mydiag, bb);
                    keptm |= 1ull << bb;
                    if (--room == 0) break;
                }
            }
            if (t == 0) keptmask_sh = keptm;
        }
        __syncthreads();
        unsigned long long keptm = keptmask_sh;
        if (t < 64 && ((keptm >> t) & 1ull)) {
            int pos = kc + __popcll(keptm & ((1ull << t) - 1ull));
            float4 bx = lbox[base + t];
            kbox[pos] = bx;
            karea[pos] = (bx.z - bx.x) * (bx.w - bx.y);
            lsel[pos] = base + t;
        }
        kc += __popcll(keptm);
        __syncthreads();
    }
    if (t == 0) kept_count[b] = kc;
    // cheap outputs from LDS: boxes (16,300,4) and scores (16,300,1)
    float* ob  = out;
    float* osc = out + BS * MAX_DET * 4;
    for (int r = t; r < MAX_DET; r += 1024) {
        int det = b * MAX_DET + r;
        if (r < kc) {
            float4 bx = kbox[r];
            ob[det * 4 + 0] = bx.x; ob[det * 4 + 1] = bx.y;
            ob[det * 4 + 2] = bx.z; ob[det * 4 + 3] = bx.w;
            osc[det] = sc_ws[b * MAX_NMS + lsel[r]];
            sel_slot[b * MAX_DET + r] = lsel[r];
        } else {
            ob[det * 4 + 0] = 0.f; ob[det * 4 + 1] = 0.f;
            ob[det * 4 + 2] = 0.f; ob[det * 4 + 3] = 0.f;
            osc[det] = 0.f;
        }
    }
}

// ---- Phase 4: wide keypoint gather (full-GPU TLP for scattered reads) ----
__global__ void k_kpt(const float* __restrict__ preds, const int* __restrict__ oidx_ws,
                      const int* __restrict__ sel_slot, const int* __restrict__ kept_count,
                      float* __restrict__ out) {
    int g = blockIdx.x * blockDim.x + threadIdx.x;   // 16*300*64 threads
    int det = g >> 6, lane = g & 63;
    if (det >= BS * MAX_DET || lane >= 51) return;
    int b = det / MAX_DET, r = det - b * MAX_DET;
    float* okp = out + BS * MAX_DET * 5;             // (16,300,51)
    if (r < kept_count[b]) {
        int s = sel_slot[b * MAX_DET + r];
        int oi = oidx_ws[b * MAX_NMS + s];
        float v = preds[(size_t)b * NCH * N_ANCH + (size_t)(5 + lane) * N_ANCH + oi];
        if (lane < 2) v = fminf(fmaxf(v, 0.f), IMG); // ref clips only cols 0,1
        okp[det * 51 + lane] = v;
    } else {
        okp[det * 51 + lane] = 0.f;
    }
}

extern "C" void kernel_launch(void* const* d_in, const int* in_sizes, int n_in,
                              void* d_out, int out_size, void* d_ws, size_t ws_size,
                              hipStream_t stream) {
    const float* preds = (const float*)d_in[0];
    float* out = (float*)d_out;
    char* ws = (char*)d_ws;
    unsigned long long* cand = (unsigned long long*)(ws + OFF_CAND);
    unsigned int* wlist = (unsigned int*)(ws + OFF_WL);
    int* wcount = (int*)(ws + OFF_WC);
    int* kept = (int*)(ws + OFF_KEPT);
    int* oidx = (int*)(ws + OFF_OIDX);
    float* sc = (float*)(ws + OFF_SC);
    int* sel = (int*)(ws + OFF_SEL);
    float4* box = (float4*)(ws + OFF_BOX);

    k_phase1<<<BS, 1024, 0, stream>>>(preds, cand, wlist, wcount, oidx, sc, box);
    k_rank2<<<dim3(BS, 32), 256, 0, stream>>>(preds, cand, wlist, wcount, oidx, sc, box);
    k_nms<<<BS, 1024, 0, stream>>>(box, sc, sel, kept, out);
    k_kpt<<<(BS * MAX_DET * 64 + 255) / 256, 256, 0, stream>>>(preds, oidx, sel, kept, out);
}